// Round 11
// baseline (123.462 us; speedup 1.0000x reference)
//
#include <hip/hip_runtime.h>

// BurstSnn: 32-step burst-encoder + 2-layer LIF SNN, B=16384, D=187, H=50, C=5.
// R19 = R18 (65.2us dispatch, absmax 0.0) + LDS-BANDWIDTH reduction in the
// sparse gather. Traffic arithmetic: ~80 trips/elem x 3 ds_read_b128 x 1KB
// x 16384 elems ~= 3.9GB + swizzles/bpermutes ~1.1GB ~= 5GB in 65us = ~77TB/s
// demanded vs ~69TB/s measured LDS ceiling -> the kernel is LDS-BW-bound
// (explains VALUBusy pinned at 75% while every VALU-count cut came back
// neutral). Two pure wastes removed, addressing-only (read values are still
// zeros -> bit-exact):
//  (a) slot waste: lanes ql=13..15 (12/64) read zero-padding at DISTINCT
//      addresses every trip. Now their row multiplier M=0 pins them to one
//      fixed (zero) slot -> same-address broadcast ~= free.
//  (b) max-padding waste: exhausted streams (f=-1) read the zero row at 16
//      distinct addresses/quarter. Now they redirect to a quarter-UNIFORM
//      16B of the group's zero row -> 16-lane broadcast.
// Cost: +2 VALU/stream/trip (cmp+cndmask+mul vs lshl_add) -- affordable at
// 75% VALUBusy. Dense path unchanged (immediate-offset addressing needs the
// padded layout; reads zeros harmlessly as before).
// Everything else identical to R18 (quiet skips, ds_swizzle merge, shfl
// combines, persistent NGEN=2, dense mode n>=21, early exit).

constexpr int D = 187;
constexpr int H = 50;
constexpr int C = 5;
constexpr int T = 32;
constexpr int WPB = 16;        // waves per block
constexpr int NGEN = 2;        // elements per wave (sequential generations)
constexpr int ROWS1 = 193;     // rows rd = 33*(d>>5) + (d&31) + 1; rd=33g zero
constexpr int RS = 64;         // floats per Wt1 row (256 B): 16 float4 slots

__device__ __forceinline__ int v_ffbl(unsigned int m) {  // -1 when m == 0
    int r;
    asm("v_ffbl_b32 %0, %1" : "=v"(r) : "v"(m));
    return r;
}

// acc.x = w.x + acc.x ; acc.y = w.y + acc.y  (one VOP3P instruction)
__device__ __forceinline__ void pk_add(float2& acc, float2 w) {
    asm("v_pk_add_f32 %0, %1, %0" : "+v"(acc) : "v"(w));
}

// m = a*m + c  (per component, fused)
__device__ __forceinline__ void pk_fma(float2& m, float2 a, float2 c) {
    asm("v_pk_fma_f32 %0, %1, %0, %2" : "+v"(m) : "v"(a), "v"(c));
}

// acc = s.lo * w + acc  (scalar broadcast via op_sel_hi)
__device__ __forceinline__ void pk_fma_b(float2& acc, float2 s, float2 w) {
    asm("v_pk_fma_f32 %0, %2, %1, %0 op_sel:[0,0,0] op_sel_hi:[0,1,1]"
        : "+v"(acc) : "v"(w), "v"(s));
}

// lane l <-> l^16 within each 32-lane half (LDS pipe; verified absmax 0.0)
__device__ __forceinline__ float2 sw16(float2 v) {
    float2 r;
    r.x = __int_as_float(__builtin_amdgcn_ds_swizzle(__float_as_int(v.x), 0x401F));
    r.y = __int_as_float(__builtin_amdgcn_ds_swizzle(__float_as_int(v.y), 0x401F));
    return r;
}

__global__ __launch_bounds__(1024, 8)
void burst_snn_kernel(const float* __restrict__ x,
                      const float* __restrict__ W1,
                      const float* __restrict__ W2,
                      float* __restrict__ out, int B) {
    __shared__ float Wt1[ROWS1 * RS];   // 12352 floats = 48.25 KB
    // Wt2: 64 rows x 16 floats. rows 1..25: h=0..24; rows 27..51: h=25..49.
    __shared__ float Wt2[1024];         // 4 KB

    const int tid = threadIdx.x;
    for (int idx = tid; idx < ROWS1 * RS; idx += 1024) {
        int rd = idx >> 6, j = idx & 63;
        int g = rd / 33;
        bool zrow = (rd == 33 * g);
        int d = rd - 1 - g;
        int slot = j >> 2, c = j & 3;
        int h = 13 * c + slot;
        float v = 0.f;
        if (!zrow && slot < 13 && h < H) v = W1[h * D + d];
        Wt1[idx] = v;
    }
    {
        int r = tid >> 4, c = tid & 15;   // tid covers all 1024
        int h = -1;
        if (r >= 1 && r <= 25) h = r - 1;
        else if (r >= 27 && r <= 51) h = r - 2;
        float v = 0.f;
        if (h >= 0 && c < C) v = W2[c * H + h];
        Wt2[tid] = v;
    }
    __syncthreads();

    const int lane = tid & 63;
    const bool isLo = lane < 32;
    const int qOdd = (lane >> 4) & 1;    // quarters 1,3 handle odd groups
    const int ql = lane & 15;            // float4 slot within a row (ql<13 live)

    // Gather bases: stream s covers groups {2s (even quarters), 2s+1 (odd)}.
    const char* wb = (const char*)Wt1;
    const int qbase = ql * 16 + (qOdd ? (33 << 8) : 0) + 256;
    const char* bs0 = wb + qbase;               // groups 0/1
    const char* bs1 = wb + qbase + (66 << 8);   // groups 2/3
    const char* bs2 = wb + qbase + (132 << 8);  // groups 4/5

    // Sparse-path addressing: per-lane row multiplier (padding lanes pinned
    // to one zero slot -> broadcast) and quarter-uniform zero-row targets
    // for exhausted streams (16-lane broadcast). Values read are all zeros.
    const int M = (ql < 13) ? 256 : 0;
    const char* zp0 = wb + ((33 * (0 + qOdd)) << 8);   // zero row of group 2*0+qOdd
    const char* zp1 = wb + ((33 * (2 + qOdd)) << 8);   // zero row of group 2*1+qOdd
    const char* zp2 = wb + ((33 * (4 + qOdd)) << 8);   // zero row of group 2*2+qOdd

    // L2 quarter scan: q0..q3 scan {lo_t, hi_t, lo_u, hi_u}.
    const float* base2 = Wt2 + ((qOdd ? 27 : 1) << 4) + ql;

    const float2 beta2 = make_float2(0.9f, 0.9f);
    const float2 neg1 = make_float2(-1.0f, -1.0f);
    const float2 zero2 = make_float2(0.f, 0.f);

    float* outSpk = out;                     // [T][B][C]
    float* outCnt = out + (size_t)T * B * C; // [B]
    const unsigned BC = (unsigned)(B * C);
    const int stride = gridDim.x * WPB;      // elements per generation
    const int base = blockIdx.x * WPB + (tid >> 6);

    for (int gen = 0; gen < NGEN; ++gen) {
        const int b = base + gen * stride;
        if (b >= B) break;

        // ---------------- per-element state ----------------
        const float* xb = x + (size_t)b * D;
        float r0 = xb[lane];
        float r1 = xb[64 + lane];
        float r2 = (lane < D - 128) ? xb[128 + lane] : 0.f;
        float th0 = 0.125f, th1 = 0.125f, th2 = 0.125f;
        float2 m01 = zero2, m23 = zero2;
        float mem2 = 0.f;                // lanes 0..4: c = lane
        int cnt = 0;                     // wave-uniform (SALU popcounts)
        unsigned o0 = (unsigned)(b * C + lane);  // only lanes < C store
        unsigned int ga[6], gb[6];
        int tDone = T;

        for (int t = 0; t < T; t += 2) {
            // --- two encoder steps (exact fp32 sequence), masks for t and t+1
            {
                bool s0 = r0 >= th0, s1 = r1 >= th1, s2 = r2 >= th2;
                r0 -= s0 ? th0 : 0.f; th0 = s0 ? th0 + th0 : 0.125f;
                r1 -= s1 ? th1 : 0.f; th1 = s1 ? th1 + th1 : 0.125f;
                r2 -= s2 ? th2 : 0.f; th2 = s2 ? th2 + th2 : 0.125f;
                unsigned long long B0 = __ballot(s0), B1 = __ballot(s1), B2 = __ballot(s2);
                ga[0] = (unsigned)B0; ga[1] = (unsigned)(B0 >> 32);
                ga[2] = (unsigned)B1; ga[3] = (unsigned)(B1 >> 32);
                ga[4] = (unsigned)B2; ga[5] = (unsigned)(B2 >> 32);
            }
            {
                bool s0 = r0 >= th0, s1 = r1 >= th1, s2 = r2 >= th2;
                r0 -= s0 ? th0 : 0.f; th0 = s0 ? th0 + th0 : 0.125f;
                r1 -= s1 ? th1 : 0.f; th1 = s1 ? th1 + th1 : 0.125f;
                r2 -= s2 ? th2 : 0.f; th2 = s2 ? th2 + th2 : 0.125f;
                unsigned long long B0 = __ballot(s0), B1 = __ballot(s1), B2 = __ballot(s2);
                gb[0] = (unsigned)B0; gb[1] = (unsigned)(B0 >> 32);
                gb[2] = (unsigned)B1; gb[3] = (unsigned)(B1 >> 32);
                gb[4] = (unsigned)B2; gb[5] = (unsigned)(B2 >> 32);
            }

            unsigned encAny = ga[0] | ga[1] | ga[2] | ga[3] | ga[4] | ga[5]
                            | gb[0] | gb[1] | gb[2] | gb[3] | gb[4] | gb[5];

            float2 cml, cmh, cu01, cu23;
            if (encAny) {
                // SALU: spike count + trip count (max of 12)
                int pa0 = __popc(ga[0]), pa1 = __popc(ga[1]), pa2 = __popc(ga[2]);
                int pa3 = __popc(ga[3]), pa4 = __popc(ga[4]), pa5 = __popc(ga[5]);
                int pb0 = __popc(gb[0]), pb1 = __popc(gb[1]), pb2 = __popc(gb[2]);
                int pb3 = __popc(gb[3]), pb4 = __popc(gb[4]), pb5 = __popc(gb[5]);
                cnt += (pa0 + pa1) + (pa2 + pa3) + (pa4 + pa5)
                     + (pb0 + pb1) + (pb2 + pb3) + (pb4 + pb5);
                int ma = max(max(max(pa0, pa1), max(pa2, pa3)), max(pa4, pa5));
                int mb = max(max(max(pb0, pb1), max(pb2, pb3)), max(pb4, pb5));
                int n = max(ma, mb);

                // Per-lane stream masks: quarter scans (group 2s+qOdd, t/u)
                unsigned e0 = isLo ? ga[0] : gb[0], d0 = isLo ? ga[1] : gb[1];
                unsigned e1 = isLo ? ga[2] : gb[2], d1 = isLo ? ga[3] : gb[3];
                unsigned e2 = isLo ? ga[4] : gb[4], d2 = isLo ? ga[5] : gb[5];
                unsigned vm0 = qOdd ? d0 : e0;
                unsigned vm1 = qOdd ? d1 : e1;
                unsigned vm2 = qOdd ? d2 : e2;

                // --- L1 gather
                float2 a0l = zero2, a0h = zero2;
                float2 a1l = zero2, a1h = zero2;
                float2 a2l = zero2, a2h = zero2;
                if (n >= 21) {
                    // DENSE: full unrolled scan, compile-time ds offsets,
                    // spike bit -> {0.0,1.0} multiplier (broadcast fma).
                    float2 sv0 = zero2, sv1 = zero2, sv2 = zero2;
                    #pragma unroll
                    for (int f = 0; f < 32; ++f) {
                        sv0.x = (float)((vm0 >> f) & 1u);
                        sv1.x = (float)((vm1 >> f) & 1u);
                        sv2.x = (float)((vm2 >> f) & 1u);
                        const char* p0 = bs0 + (f << 8);
                        const char* p1 = bs1 + (f << 8);
                        const char* p2 = bs2 + (f << 8);
                        float2 w0l = *(const float2*)p0, w0h = *(const float2*)(p0 + 8);
                        float2 w1l = *(const float2*)p1, w1h = *(const float2*)(p1 + 8);
                        float2 w2l = *(const float2*)p2, w2h = *(const float2*)(p2 + 8);
                        pk_fma_b(a0l, sv0, w0l); pk_fma_b(a0h, sv0, w0h);
                        pk_fma_b(a1l, sv1, w1l); pk_fma_b(a1h, sv1, w1h);
                        pk_fma_b(a2l, sv2, w2l); pk_fma_b(a2h, sv2, w2h);
                    }
                } else {
                    // SPARSE: 3 streams, one 16B row chunk per stream-trip.
                    // Padding lanes (M=0) and exhausted streams (f<0) read
                    // fixed zero slots -> same-address broadcast, ~free BW.
                    for (; n > 0; --n) {
                        int f0 = v_ffbl(vm0); vm0 &= vm0 - 1;
                        int f1 = v_ffbl(vm1); vm1 &= vm1 - 1;
                        int f2 = v_ffbl(vm2); vm2 &= vm2 - 1;
                        const char* p0 = (f0 >= 0) ? bs0 + f0 * M : zp0;
                        const char* p1 = (f1 >= 0) ? bs1 + f1 * M : zp1;
                        const char* p2 = (f2 >= 0) ? bs2 + f2 * M : zp2;
                        float2 w0l = *(const float2*)p0, w0h = *(const float2*)(p0 + 8);
                        float2 w1l = *(const float2*)p1, w1h = *(const float2*)(p1 + 8);
                        float2 w2l = *(const float2*)p2, w2h = *(const float2*)(p2 + 8);
                        pk_add(a0l, w0l); pk_add(a0h, w0h);
                        pk_add(a1l, w1l); pk_add(a1h, w1h);
                        pk_add(a2l, w2l); pk_add(a2h, w2h);
                    }
                }

                // --- merge: odd-group partials to even quarters (xor-16
                //     ds_swizzle, verified); order g0..g5 pairwise-left.
                float2 s0l = sw16(a0l), s0h = sw16(a0h);
                float2 s1l = sw16(a1l), s1h = sw16(a1h);
                float2 s2l = sw16(a2l), s2h = sw16(a2h);
                cml = a0l; cmh = a0h;
                pk_add(cml, s0l); pk_add(cmh, s0h);   // +g1
                pk_add(cml, a1l); pk_add(cmh, a1h);   // +g2
                pk_add(cml, s1l); pk_add(cmh, s1h);   // +g3
                pk_add(cml, a2l); pk_add(cmh, a2h);   // +g4
                pk_add(cml, s2l); pk_add(cmh, s2h);   // +g5
                // cur1 float4 on lanes 0-12 (t) and 32-44 (t+1)
                cu01 = make_float2(__shfl_down(cml.x, 32), __shfl_down(cml.y, 32));
                cu23 = make_float2(__shfl_down(cmh.x, 32), __shfl_down(cmh.y, 32));
            } else {
                cml = zero2; cmh = zero2; cu01 = zero2; cu23 = zero2;
            }

            // --- LIF layer 1, step t (lanes 0-12; pads have zero weights)
            pk_fma(m01, beta2, cml);
            pk_fma(m23, beta2, cmh);
            float2 d01 = m01, d23 = m23;
            pk_add(d01, neg1); pk_add(d23, neg1);
            bool t0 = d01.x > 0.f, t1 = d01.y > 0.f;
            bool t2 = d23.x > 0.f, t3 = d23.y > 0.f;
            unsigned long long Pa = __ballot(t0), Pb = __ballot(t1);
            unsigned long long Pc = __ballot(t2), Pd = __ballot(t3);
            m01.x = t0 ? d01.x : m01.x;  m01.y = t1 ? d01.y : m01.y;
            m23.x = t2 ? d23.x : m23.x;  m23.y = t3 ? d23.y : m23.y;
            unsigned c0t = (unsigned)Pa & 0x1FFFu;
            unsigned c1t = (unsigned)Pb & 0x1FFFu;
            unsigned c2t = (unsigned)Pc & 0x1FFFu;
            unsigned c3t = (unsigned)Pd & 0x1FFFu;
            // --- LIF layer 1, step t+1
            pk_fma(m01, beta2, cu01);
            pk_fma(m23, beta2, cu23);
            float2 e01 = m01, e23 = m23;
            pk_add(e01, neg1); pk_add(e23, neg1);
            bool u0 = e01.x > 0.f, u1 = e01.y > 0.f;
            bool u2 = e23.x > 0.f, u3 = e23.y > 0.f;
            unsigned long long Qa = __ballot(u0), Qb = __ballot(u1);
            unsigned long long Qc = __ballot(u2), Qd = __ballot(u3);
            m01.x = u0 ? e01.x : m01.x;  m01.y = u1 ? e01.y : m01.y;
            m23.x = u2 ? e23.x : m23.x;  m23.y = u3 ? e23.y : m23.y;
            unsigned c0u = (unsigned)Qa & 0x1FFFu;
            unsigned c1u = (unsigned)Qb & 0x1FFFu;
            unsigned c2u = (unsigned)Qc & 0x1FFFu;
            unsigned c3u = (unsigned)Qd & 0x1FFFu;

            // h-ordered spike masks (h = 13c + l): shift-OR only (SALU)
            unsigned lo_t = c0t | ((c1t & 0xFFFu) << 13);           // h 0..24
            unsigned hi_t = (c1t >> 12) | (c2t << 1) | ((c3t & 0x7FFu) << 14); // h 25..49
            unsigned lo_u = c0u | ((c1u & 0xFFFu) << 13);
            unsigned hi_u = (c1u >> 12) | (c2u << 1) | ((c3u & 0x7FFu) << 14);
            unsigned l1Any = lo_t | hi_t | lo_u | hi_u;

            // --- layer-2 quarter gather: q0..q3 scan {lo_t,hi_t,lo_u,hi_u}
            float cur2, c2t1;
            if (l1Any) {
                int p0c = __popc(lo_t), p1c = __popc(hi_t);
                int p2c = __popc(lo_u), p3c = __popc(hi_u);
                int n2 = max(max(p0c, p1c), max(p2c, p3c));
                float cq = 0.f;
                unsigned vmq = isLo ? (qOdd ? hi_t : lo_t) : (qOdd ? hi_u : lo_u);
                for (; n2 > 0; --n2) {
                    int f = v_ffbl(vmq); vmq &= vmq - 1;
                    cq += *(base2 + f * 16);
                }
                // combine quarters: lanes 0..4 get (lo+hi) for t; t+1 from +32
                float tmp = cq + __shfl_down(cq, 16);
                cur2 = tmp;                          // step t   (lanes 0..4)
                c2t1 = __shfl_down(tmp, 32);         // step t+1 (lanes 0..4)
            } else {
                cur2 = 0.f; c2t1 = 0.f;
            }

            // --- LIF layer 2, step t
            mem2 = 0.9f * mem2 + cur2;
            bool sp2 = (mem2 - 1.0f > 0.f);
            mem2 -= sp2 ? 1.0f : 0.f;
            if (lane < C) outSpk[o0] = sp2 ? 1.0f : 0.0f;
            // --- LIF layer 2, step t+1
            mem2 = 0.9f * mem2 + c2t1;
            bool sp2b = (mem2 - 1.0f > 0.f);
            mem2 -= sp2b ? 1.0f : 0.f;
            if (lane < C) outSpk[o0 + BC] = sp2b ? 1.0f : 0.0f;
            o0 += 2u * BC;

            // --- early exit: SALU quiet gate, then exact dead check.
            if ((encAny | l1Any) == 0u) {
                float rm = fmaxf(fmaxf(r0, r1), r2);        // residuals >= 0
                unsigned long long am = __ballot(rm >= 0.125f);
                float mm = fmaxf(fmaxf(m01.x, m01.y), fmaxf(m23.x, m23.y));
                unsigned long long m1 = __ballot(mm > 1.0f) & 0x1FFFull;
                unsigned long long m2 = __ballot(mem2 > 1.0f) & 0x1Full;
                if ((am | m1 | m2) == 0ull) { tDone = t + 2; break; }
            }
        }

        // --- zero-fill the provably-silent tail steps
        if (lane < C) {
            for (int tt = tDone; tt < T; ++tt) {
                outSpk[o0] = 0.0f;
                o0 += BC;
            }
        }
        // --- spike count (wave-uniform), write counts[b]
        if (lane == 0) outCnt[b] = (float)cnt;
    }
}

extern "C" void kernel_launch(void* const* d_in, const int* in_sizes, int n_in,
                              void* d_out, int out_size, void* d_ws, size_t ws_size,
                              hipStream_t stream) {
    const float* x  = (const float*)d_in[0];
    const float* W1 = (const float*)d_in[1];
    const float* W2 = (const float*)d_in[2];
    float* out = (float*)d_out;
    const int B = in_sizes[0] / D;
    int blocks = (B + WPB * NGEN - 1) / (WPB * NGEN);  // 512 for B=16384
    burst_snn_kernel<<<blocks, 1024, 0, stream>>>(x, W1, W2, out, B);
}

// Round 12
// 117.686 us; speedup vs baseline: 1.0491x; 1.0491x over previous
//
#include <hip/hip_runtime.h>

// BurstSnn: 32-step burst-encoder + 2-layer LIF SNN, B=16384, D=187, H=50, C=5.
// R20 = R18 VERBATIM (best verified: 65.2us dispatch, absmax 0.0).
// R19's zero-slot addressing is REVERTED: SQ_LDS_BANK_CONFLICT 318K->2.05M,
// +5us. Lesson: ds_read_b128 executes as 4x 16-lane phases, 1 clock per
// conflict-free phase; R18's one-contiguous-row-per-phase pattern is already
// optimal, and LDS cost is phase-count-bound, not distinct-byte-bound --
// "deduplicating" bytes inside a phase saves nothing and breaks the pattern.
// Structure (accumulated, all verified absmax 0.0):
//  - quarter-wave float4 gather: Wt1 row d = 16 float4 slots, slot l comp c
//    = W1[h=13c+l,d]; quarters scan {even-groups@t, odd@t, even@t+1, odd@t+1};
//    1 ds_read_b128 per stream-trip = 4 rows; trips = max of 12 popcounts.
//  - DENSE mode (n>=21): fully-unrolled 32-row scan, compile-time ds offsets,
//    spike bit -> {0,1} multiplier via broadcast pk_fma.
//  - merge via ds_swizzle xor-16 + pairwise-left g0..g5; shfl_down combines.
//  - wave-uniform quiet skips (encAny==0 / l1Any==0), bit-exact.
//  - persistent NGEN=2 schedule: 512 blocks, waves roll into element b+8192.
//  - early exit + zero-fill when {all r<0.125, mem1<=1, mem2<=1} (dead state).

constexpr int D = 187;
constexpr int H = 50;
constexpr int C = 5;
constexpr int T = 32;
constexpr int WPB = 16;        // waves per block
constexpr int NGEN = 2;        // elements per wave (sequential generations)
constexpr int ROWS1 = 193;     // rows rd = 33*(d>>5) + (d&31) + 1; rd=33g zero
constexpr int RS = 64;         // floats per Wt1 row (256 B): 16 float4 slots

__device__ __forceinline__ int v_ffbl(unsigned int m) {  // -1 when m == 0
    int r;
    asm("v_ffbl_b32 %0, %1" : "=v"(r) : "v"(m));
    return r;
}

// acc.x = w.x + acc.x ; acc.y = w.y + acc.y  (one VOP3P instruction)
__device__ __forceinline__ void pk_add(float2& acc, float2 w) {
    asm("v_pk_add_f32 %0, %1, %0" : "+v"(acc) : "v"(w));
}

// m = a*m + c  (per component, fused)
__device__ __forceinline__ void pk_fma(float2& m, float2 a, float2 c) {
    asm("v_pk_fma_f32 %0, %1, %0, %2" : "+v"(m) : "v"(a), "v"(c));
}

// acc = s.lo * w + acc  (scalar broadcast via op_sel_hi)
__device__ __forceinline__ void pk_fma_b(float2& acc, float2 s, float2 w) {
    asm("v_pk_fma_f32 %0, %2, %1, %0 op_sel:[0,0,0] op_sel_hi:[0,1,1]"
        : "+v"(acc) : "v"(w), "v"(s));
}

// lane l <-> l^16 within each 32-lane half (LDS pipe; verified absmax 0.0)
__device__ __forceinline__ float2 sw16(float2 v) {
    float2 r;
    r.x = __int_as_float(__builtin_amdgcn_ds_swizzle(__float_as_int(v.x), 0x401F));
    r.y = __int_as_float(__builtin_amdgcn_ds_swizzle(__float_as_int(v.y), 0x401F));
    return r;
}

__global__ __launch_bounds__(1024, 8)
void burst_snn_kernel(const float* __restrict__ x,
                      const float* __restrict__ W1,
                      const float* __restrict__ W2,
                      float* __restrict__ out, int B) {
    __shared__ float Wt1[ROWS1 * RS];   // 12352 floats = 48.25 KB
    // Wt2: 64 rows x 16 floats. rows 1..25: h=0..24; rows 27..51: h=25..49.
    __shared__ float Wt2[1024];         // 4 KB

    const int tid = threadIdx.x;
    for (int idx = tid; idx < ROWS1 * RS; idx += 1024) {
        int rd = idx >> 6, j = idx & 63;
        int g = rd / 33;
        bool zrow = (rd == 33 * g);
        int d = rd - 1 - g;
        int slot = j >> 2, c = j & 3;
        int h = 13 * c + slot;
        float v = 0.f;
        if (!zrow && slot < 13 && h < H) v = W1[h * D + d];
        Wt1[idx] = v;
    }
    {
        int r = tid >> 4, c = tid & 15;   // tid covers all 1024
        int h = -1;
        if (r >= 1 && r <= 25) h = r - 1;
        else if (r >= 27 && r <= 51) h = r - 2;
        float v = 0.f;
        if (h >= 0 && c < C) v = W2[c * H + h];
        Wt2[tid] = v;
    }
    __syncthreads();

    const int lane = tid & 63;
    const bool isLo = lane < 32;
    const int qOdd = (lane >> 4) & 1;    // quarters 1,3 handle odd groups
    const int ql = lane & 15;            // float4 slot within a row (ql<13 live)

    // Gather bases: stream s covers groups {2s (even quarters), 2s+1 (odd)}.
    const char* wb = (const char*)Wt1;
    const int qbase = ql * 16 + (qOdd ? (33 << 8) : 0) + 256;
    const char* bs0 = wb + qbase;               // groups 0/1
    const char* bs1 = wb + qbase + (66 << 8);   // groups 2/3
    const char* bs2 = wb + qbase + (132 << 8);  // groups 4/5

    // L2 quarter scan: q0..q3 scan {lo_t, hi_t, lo_u, hi_u}.
    const float* base2 = Wt2 + ((qOdd ? 27 : 1) << 4) + ql;

    const float2 beta2 = make_float2(0.9f, 0.9f);
    const float2 neg1 = make_float2(-1.0f, -1.0f);
    const float2 zero2 = make_float2(0.f, 0.f);

    float* outSpk = out;                     // [T][B][C]
    float* outCnt = out + (size_t)T * B * C; // [B]
    const unsigned BC = (unsigned)(B * C);
    const int stride = gridDim.x * WPB;      // elements per generation
    const int base = blockIdx.x * WPB + (tid >> 6);

    for (int gen = 0; gen < NGEN; ++gen) {
        const int b = base + gen * stride;
        if (b >= B) break;

        // ---------------- per-element state ----------------
        const float* xb = x + (size_t)b * D;
        float r0 = xb[lane];
        float r1 = xb[64 + lane];
        float r2 = (lane < D - 128) ? xb[128 + lane] : 0.f;
        float th0 = 0.125f, th1 = 0.125f, th2 = 0.125f;
        float2 m01 = zero2, m23 = zero2;
        float mem2 = 0.f;                // lanes 0..4: c = lane
        int cnt = 0;                     // wave-uniform (SALU popcounts)
        unsigned o0 = (unsigned)(b * C + lane);  // only lanes < C store
        unsigned int ga[6], gb[6];
        int tDone = T;

        for (int t = 0; t < T; t += 2) {
            // --- two encoder steps (exact fp32 sequence), masks for t and t+1
            {
                bool s0 = r0 >= th0, s1 = r1 >= th1, s2 = r2 >= th2;
                r0 -= s0 ? th0 : 0.f; th0 = s0 ? th0 + th0 : 0.125f;
                r1 -= s1 ? th1 : 0.f; th1 = s1 ? th1 + th1 : 0.125f;
                r2 -= s2 ? th2 : 0.f; th2 = s2 ? th2 + th2 : 0.125f;
                unsigned long long B0 = __ballot(s0), B1 = __ballot(s1), B2 = __ballot(s2);
                ga[0] = (unsigned)B0; ga[1] = (unsigned)(B0 >> 32);
                ga[2] = (unsigned)B1; ga[3] = (unsigned)(B1 >> 32);
                ga[4] = (unsigned)B2; ga[5] = (unsigned)(B2 >> 32);
            }
            {
                bool s0 = r0 >= th0, s1 = r1 >= th1, s2 = r2 >= th2;
                r0 -= s0 ? th0 : 0.f; th0 = s0 ? th0 + th0 : 0.125f;
                r1 -= s1 ? th1 : 0.f; th1 = s1 ? th1 + th1 : 0.125f;
                r2 -= s2 ? th2 : 0.f; th2 = s2 ? th2 + th2 : 0.125f;
                unsigned long long B0 = __ballot(s0), B1 = __ballot(s1), B2 = __ballot(s2);
                gb[0] = (unsigned)B0; gb[1] = (unsigned)(B0 >> 32);
                gb[2] = (unsigned)B1; gb[3] = (unsigned)(B1 >> 32);
                gb[4] = (unsigned)B2; gb[5] = (unsigned)(B2 >> 32);
            }

            unsigned encAny = ga[0] | ga[1] | ga[2] | ga[3] | ga[4] | ga[5]
                            | gb[0] | gb[1] | gb[2] | gb[3] | gb[4] | gb[5];

            float2 cml, cmh, cu01, cu23;
            if (encAny) {
                // SALU: spike count + trip count (max of 12)
                int pa0 = __popc(ga[0]), pa1 = __popc(ga[1]), pa2 = __popc(ga[2]);
                int pa3 = __popc(ga[3]), pa4 = __popc(ga[4]), pa5 = __popc(ga[5]);
                int pb0 = __popc(gb[0]), pb1 = __popc(gb[1]), pb2 = __popc(gb[2]);
                int pb3 = __popc(gb[3]), pb4 = __popc(gb[4]), pb5 = __popc(gb[5]);
                cnt += (pa0 + pa1) + (pa2 + pa3) + (pa4 + pa5)
                     + (pb0 + pb1) + (pb2 + pb3) + (pb4 + pb5);
                int ma = max(max(max(pa0, pa1), max(pa2, pa3)), max(pa4, pa5));
                int mb = max(max(max(pb0, pb1), max(pb2, pb3)), max(pb4, pb5));
                int n = max(ma, mb);

                // Per-lane stream masks: quarter scans (group 2s+qOdd, t/u)
                unsigned e0 = isLo ? ga[0] : gb[0], d0 = isLo ? ga[1] : gb[1];
                unsigned e1 = isLo ? ga[2] : gb[2], d1 = isLo ? ga[3] : gb[3];
                unsigned e2 = isLo ? ga[4] : gb[4], d2 = isLo ? ga[5] : gb[5];
                unsigned vm0 = qOdd ? d0 : e0;
                unsigned vm1 = qOdd ? d1 : e1;
                unsigned vm2 = qOdd ? d2 : e2;

                // --- L1 gather
                float2 a0l = zero2, a0h = zero2;
                float2 a1l = zero2, a1h = zero2;
                float2 a2l = zero2, a2h = zero2;
                if (n >= 21) {
                    // DENSE: full unrolled scan, compile-time ds offsets,
                    // spike bit -> {0.0,1.0} multiplier (broadcast fma).
                    float2 sv0 = zero2, sv1 = zero2, sv2 = zero2;
                    #pragma unroll
                    for (int f = 0; f < 32; ++f) {
                        sv0.x = (float)((vm0 >> f) & 1u);
                        sv1.x = (float)((vm1 >> f) & 1u);
                        sv2.x = (float)((vm2 >> f) & 1u);
                        const char* p0 = bs0 + (f << 8);
                        const char* p1 = bs1 + (f << 8);
                        const char* p2 = bs2 + (f << 8);
                        float2 w0l = *(const float2*)p0, w0h = *(const float2*)(p0 + 8);
                        float2 w1l = *(const float2*)p1, w1h = *(const float2*)(p1 + 8);
                        float2 w2l = *(const float2*)p2, w2h = *(const float2*)(p2 + 8);
                        pk_fma_b(a0l, sv0, w0l); pk_fma_b(a0h, sv0, w0h);
                        pk_fma_b(a1l, sv1, w1l); pk_fma_b(a1h, sv1, w1h);
                        pk_fma_b(a2l, sv2, w2l); pk_fma_b(a2h, sv2, w2h);
                    }
                } else {
                    // SPARSE: 3 streams, one 16B row chunk per stream-trip
                    for (; n > 0; --n) {
                        int f0 = v_ffbl(vm0); vm0 &= vm0 - 1;
                        int f1 = v_ffbl(vm1); vm1 &= vm1 - 1;
                        int f2 = v_ffbl(vm2); vm2 &= vm2 - 1;
                        const char* p0 = bs0 + (f0 << 8);
                        const char* p1 = bs1 + (f1 << 8);
                        const char* p2 = bs2 + (f2 << 8);
                        float2 w0l = *(const float2*)p0, w0h = *(const float2*)(p0 + 8);
                        float2 w1l = *(const float2*)p1, w1h = *(const float2*)(p1 + 8);
                        float2 w2l = *(const float2*)p2, w2h = *(const float2*)(p2 + 8);
                        pk_add(a0l, w0l); pk_add(a0h, w0h);
                        pk_add(a1l, w1l); pk_add(a1h, w1h);
                        pk_add(a2l, w2l); pk_add(a2h, w2h);
                    }
                }

                // --- merge: odd-group partials to even quarters (xor-16
                //     ds_swizzle, verified); order g0..g5 pairwise-left.
                float2 s0l = sw16(a0l), s0h = sw16(a0h);
                float2 s1l = sw16(a1l), s1h = sw16(a1h);
                float2 s2l = sw16(a2l), s2h = sw16(a2h);
                cml = a0l; cmh = a0h;
                pk_add(cml, s0l); pk_add(cmh, s0h);   // +g1
                pk_add(cml, a1l); pk_add(cmh, a1h);   // +g2
                pk_add(cml, s1l); pk_add(cmh, s1h);   // +g3
                pk_add(cml, a2l); pk_add(cmh, a2h);   // +g4
                pk_add(cml, s2l); pk_add(cmh, s2h);   // +g5
                // cur1 float4 on lanes 0-12 (t) and 32-44 (t+1)
                cu01 = make_float2(__shfl_down(cml.x, 32), __shfl_down(cml.y, 32));
                cu23 = make_float2(__shfl_down(cmh.x, 32), __shfl_down(cmh.y, 32));
            } else {
                cml = zero2; cmh = zero2; cu01 = zero2; cu23 = zero2;
            }

            // --- LIF layer 1, step t (lanes 0-12; pads have zero weights)
            pk_fma(m01, beta2, cml);
            pk_fma(m23, beta2, cmh);
            float2 d01 = m01, d23 = m23;
            pk_add(d01, neg1); pk_add(d23, neg1);
            bool t0 = d01.x > 0.f, t1 = d01.y > 0.f;
            bool t2 = d23.x > 0.f, t3 = d23.y > 0.f;
            unsigned long long Pa = __ballot(t0), Pb = __ballot(t1);
            unsigned long long Pc = __ballot(t2), Pd = __ballot(t3);
            m01.x = t0 ? d01.x : m01.x;  m01.y = t1 ? d01.y : m01.y;
            m23.x = t2 ? d23.x : m23.x;  m23.y = t3 ? d23.y : m23.y;
            unsigned c0t = (unsigned)Pa & 0x1FFFu;
            unsigned c1t = (unsigned)Pb & 0x1FFFu;
            unsigned c2t = (unsigned)Pc & 0x1FFFu;
            unsigned c3t = (unsigned)Pd & 0x1FFFu;
            // --- LIF layer 1, step t+1
            pk_fma(m01, beta2, cu01);
            pk_fma(m23, beta2, cu23);
            float2 e01 = m01, e23 = m23;
            pk_add(e01, neg1); pk_add(e23, neg1);
            bool u0 = e01.x > 0.f, u1 = e01.y > 0.f;
            bool u2 = e23.x > 0.f, u3 = e23.y > 0.f;
            unsigned long long Qa = __ballot(u0), Qb = __ballot(u1);
            unsigned long long Qc = __ballot(u2), Qd = __ballot(u3);
            m01.x = u0 ? e01.x : m01.x;  m01.y = u1 ? e01.y : m01.y;
            m23.x = u2 ? e23.x : m23.x;  m23.y = u3 ? e23.y : m23.y;
            unsigned c0u = (unsigned)Qa & 0x1FFFu;
            unsigned c1u = (unsigned)Qb & 0x1FFFu;
            unsigned c2u = (unsigned)Qc & 0x1FFFu;
            unsigned c3u = (unsigned)Qd & 0x1FFFu;

            // h-ordered spike masks (h = 13c + l): shift-OR only (SALU)
            unsigned lo_t = c0t | ((c1t & 0xFFFu) << 13);           // h 0..24
            unsigned hi_t = (c1t >> 12) | (c2t << 1) | ((c3t & 0x7FFu) << 14); // h 25..49
            unsigned lo_u = c0u | ((c1u & 0xFFFu) << 13);
            unsigned hi_u = (c1u >> 12) | (c2u << 1) | ((c3u & 0x7FFu) << 14);
            unsigned l1Any = lo_t | hi_t | lo_u | hi_u;

            // --- layer-2 quarter gather: q0..q3 scan {lo_t,hi_t,lo_u,hi_u}
            float cur2, c2t1;
            if (l1Any) {
                int p0c = __popc(lo_t), p1c = __popc(hi_t);
                int p2c = __popc(lo_u), p3c = __popc(hi_u);
                int n2 = max(max(p0c, p1c), max(p2c, p3c));
                float cq = 0.f;
                unsigned vmq = isLo ? (qOdd ? hi_t : lo_t) : (qOdd ? hi_u : lo_u);
                for (; n2 > 0; --n2) {
                    int f = v_ffbl(vmq); vmq &= vmq - 1;
                    cq += *(base2 + f * 16);
                }
                // combine quarters: lanes 0..4 get (lo+hi) for t; t+1 from +32
                float tmp = cq + __shfl_down(cq, 16);
                cur2 = tmp;                          // step t   (lanes 0..4)
                c2t1 = __shfl_down(tmp, 32);         // step t+1 (lanes 0..4)
            } else {
                cur2 = 0.f; c2t1 = 0.f;
            }

            // --- LIF layer 2, step t
            mem2 = 0.9f * mem2 + cur2;
            bool sp2 = (mem2 - 1.0f > 0.f);
            mem2 -= sp2 ? 1.0f : 0.f;
            if (lane < C) outSpk[o0] = sp2 ? 1.0f : 0.0f;
            // --- LIF layer 2, step t+1
            mem2 = 0.9f * mem2 + c2t1;
            bool sp2b = (mem2 - 1.0f > 0.f);
            mem2 -= sp2b ? 1.0f : 0.f;
            if (lane < C) outSpk[o0 + BC] = sp2b ? 1.0f : 0.0f;
            o0 += 2u * BC;

            // --- early exit: SALU quiet gate, then exact dead check.
            if ((encAny | l1Any) == 0u) {
                float rm = fmaxf(fmaxf(r0, r1), r2);        // residuals >= 0
                unsigned long long am = __ballot(rm >= 0.125f);
                float mm = fmaxf(fmaxf(m01.x, m01.y), fmaxf(m23.x, m23.y));
                unsigned long long m1 = __ballot(mm > 1.0f) & 0x1FFFull;
                unsigned long long m2 = __ballot(mem2 > 1.0f) & 0x1Full;
                if ((am | m1 | m2) == 0ull) { tDone = t + 2; break; }
            }
        }

        // --- zero-fill the provably-silent tail steps
        if (lane < C) {
            for (int tt = tDone; tt < T; ++tt) {
                outSpk[o0] = 0.0f;
                o0 += BC;
            }
        }
        // --- spike count (wave-uniform), write counts[b]
        if (lane == 0) outCnt[b] = (float)cnt;
    }
}

extern "C" void kernel_launch(void* const* d_in, const int* in_sizes, int n_in,
                              void* d_out, int out_size, void* d_ws, size_t ws_size,
                              hipStream_t stream) {
    const float* x  = (const float*)d_in[0];
    const float* W1 = (const float*)d_in[1];
    const float* W2 = (const float*)d_in[2];
    float* out = (float*)d_out;
    const int B = in_sizes[0] / D;
    int blocks = (B + WPB * NGEN - 1) / (WPB * NGEN);  // 512 for B=16384
    burst_snn_kernel<<<blocks, 1024, 0, stream>>>(x, W1, W2, out, B);
}